// Round 7
// baseline (149.700 us; speedup 1.0000x reference)
//
#include <hip/hip_runtime.h>
#include <hip/hip_bf16.h>

#define DD 128
#define EPSN 1e-12f
#define MAXDEG 64
#define EPB 2048        // edges per block (256 thr x 8) for passA/passB

typedef __attribute__((ext_vector_type(8))) short bf16x8;
typedef __attribute__((ext_vector_type(4))) float f32x4;

__device__ __forceinline__ short bfbits(float f) {
  unsigned u = __float_as_uint(f);
  u += 0x7FFF + ((u >> 16) & 1);  // round-to-nearest-even
  return (short)(u >> 16);
}
__device__ __forceinline__ float bf2f(short s) {
  return __uint_as_float(((unsigned)(unsigned short)s) << 16);
}

// ---------------- init: cvt W to bf16 + zero cnt/cnt8 ----------------
__global__ __launch_bounds__(256) void k_init(
    const float* __restrict__ Wp, const float* __restrict__ Wl,
    const float* __restrict__ Wr, short* __restrict__ Wb, int m,
    int* __restrict__ cnt, int* __restrict__ cnt8, int n)
{
  int i = blockIdx.x * 256 + threadIdx.x;
  if (i < m) {
    Wb[i]         = bfbits(Wp[i]);
    Wb[m + i]     = bfbits(Wl[i]);
    Wb[2 * m + i] = bfbits(Wr[i]);
  }
  if (i < n) cnt[i] = 0;
  if (i < 8) cnt8[i] = 0;
}

// ---------------- fused: passA (radix-partition edges) ∥ project ----------------
__global__ __launch_bounds__(256) void k_projA(
    const float* __restrict__ x, const short* __restrict__ Wpb,
    const float* __restrict__ bp, unsigned short* __restrict__ h,
    const int* __restrict__ ei, unsigned* __restrict__ seg,
    int* __restrict__ cnt8, int n, int nE, int nABlk,
    unsigned scale, int segCap)
{
  int b = blockIdx.x;
  int tid = threadIdx.x;

  if (b < nABlk) {
    // ---- passA: bin 2048 edges by dst range, write packed (d<<16)|s ----
    __shared__ int bcnt[8];
    __shared__ int bcur[8];
    if (tid < 8) bcnt[tid] = 0;
    __syncthreads();
    int base = b * EPB;
    int dv[8], sv[8], bv[8];
    bool val[8];
#pragma unroll
    for (int u = 0; u < 8; ++u) {
      int e = base + u * 256 + tid;
      val[u] = (e < nE);
      if (val[u]) {
        dv[u] = ei[nE + e];
        sv[u] = ei[e];
        bv[u] = (int)(((unsigned long long)(unsigned)dv[u] * scale) >> 32);
        atomicAdd(&bcnt[bv[u]], 1);
      }
    }
    __syncthreads();
    if (tid < 8) bcur[tid] = atomicAdd(&cnt8[tid], bcnt[tid]);
    __syncthreads();
#pragma unroll
    for (int u = 0; u < 8; ++u) {
      if (val[u]) {
        int pos = atomicAdd(&bcur[bv[u]], 1);
        if (pos < segCap)
          seg[(size_t)bv[u] * segCap + pos] =
              ((unsigned)dv[u] << 16) | (unsigned)sv[u];
      }
    }
    return;
  }

  // ---- project: h = relu(x @ Wp^T + bp), split-bf16 x, MFMA ----
  int l = tid & 63;
  int wid = ((b - nABlk) * 256 + tid) >> 6;
  int row0 = wid * 16;
  if (row0 >= n) return;
  int lr = l & 15, kg = l >> 4;
  int rA = row0 + lr; if (rA > n - 1) rA = n - 1;

  f32x4 acc[8];
#pragma unroll
  for (int cb = 0; cb < 8; ++cb) {
    float bv2 = bp[16 * cb + lr];
    acc[cb] = (f32x4){bv2, bv2, bv2, bv2};
  }

  const float* xrow = x + (size_t)rA * DD;
#pragma unroll
  for (int ks = 0; ks < 4; ++ks) {
    int ko = 32 * ks + 8 * kg;
    float4 f0 = *(const float4*)(xrow + ko);
    float4 f1 = *(const float4*)(xrow + ko + 4);
    float fv[8] = {f0.x, f0.y, f0.z, f0.w, f1.x, f1.y, f1.z, f1.w};
    bf16x8 ah, al;
#pragma unroll
    for (int j = 0; j < 8; ++j) {
      short hb = bfbits(fv[j]);
      ah[j] = hb;
      al[j] = bfbits(fv[j] - bf2f(hb));
    }
#pragma unroll
    for (int cb = 0; cb < 8; ++cb) {
      bf16x8 bfr = *(const bf16x8*)(Wpb + ((16 * cb + lr) * DD + ko));
      acc[cb] = __builtin_amdgcn_mfma_f32_16x16x32_bf16(ah, bfr, acc[cb], 0, 0, 0);
      acc[cb] = __builtin_amdgcn_mfma_f32_16x16x32_bf16(al, bfr, acc[cb], 0, 0, 0);
    }
  }

#pragma unroll
  for (int i = 0; i < 4; ++i) {
    int r = row0 + 4 * kg + i;
    if (r < n) {
#pragma unroll
      for (int cb = 0; cb < 8; ++cb) {
        float v = fmaxf(acc[cb][i], 0.f);
        h[(size_t)r * DD + 16 * cb + lr] = (unsigned short)bfbits(v);
      }
    }
  }
}

// ---------------- passB: L2-resident scatter into slot buckets ----------------
// b&7 = range (XCD-affine under round-robin dispatch; correctness independent)
__global__ __launch_bounds__(256) void k_passB(
    const unsigned* __restrict__ seg, const int* __restrict__ cnt8,
    int* __restrict__ cnt, unsigned short* __restrict__ slots, int segCap)
{
  int b = blockIdx.x;
  int tid = threadIdx.x;
  int r = b & 7;
  int chunk = b >> 3;
  int len = cnt8[r]; if (len > segCap) len = segCap;
  const unsigned* s = seg + (size_t)r * segCap;
  int base = chunk * EPB;
#pragma unroll
  for (int u = 0; u < 8; ++u) {
    int e = base + u * 256 + tid;
    if (e < len) {
      unsigned p = s[e];
      int d = (int)(p >> 16);
      int src = (int)(p & 0xFFFFu);
      int pos = atomicAdd(&cnt[d], 1);
      if (pos < MAXDEG) slots[(size_t)d * MAXDEG + pos] = (unsigned short)src;
    }
  }
}

// ---------------- gather-reduce: 4 nodes per wave ----------------
__global__ __launch_bounds__(256) void k_gather(
    const int* __restrict__ cnt, const unsigned short* __restrict__ slots,
    const __hip_bfloat162* __restrict__ h2,
    __hip_bfloat162* __restrict__ meanb, int n)
{
  int w = (blockIdx.x * 256 + threadIdx.x) >> 6;
  int l = threadIdx.x & 63;
  int node0 = w * 4;
  if (node0 >= n) return;

#pragma unroll 1
  for (int i = 0; i < 4; ++i) {
    int node = node0 + i;
    if (node >= n) break;
    int dgTrue = cnt[node];
    int dg = dgTrue < MAXDEG ? dgTrue : MAXDEG;
    int myidx = (int)slots[(size_t)node * MAXDEG + l];

    float s0 = 0.f, s1 = 0.f, t0 = 0.f, t1 = 0.f;
    int j = 0;
    for (; j + 8 <= dg; j += 8) {
      int i0 = __builtin_amdgcn_readlane(myidx, j);
      int i1 = __builtin_amdgcn_readlane(myidx, j + 1);
      int i2 = __builtin_amdgcn_readlane(myidx, j + 2);
      int i3 = __builtin_amdgcn_readlane(myidx, j + 3);
      int i4 = __builtin_amdgcn_readlane(myidx, j + 4);
      int i5 = __builtin_amdgcn_readlane(myidx, j + 5);
      int i6 = __builtin_amdgcn_readlane(myidx, j + 6);
      int i7 = __builtin_amdgcn_readlane(myidx, j + 7);
      __hip_bfloat162 v0 = h2[(size_t)i0 * 64 + l];
      __hip_bfloat162 v1 = h2[(size_t)i1 * 64 + l];
      __hip_bfloat162 v2 = h2[(size_t)i2 * 64 + l];
      __hip_bfloat162 v3 = h2[(size_t)i3 * 64 + l];
      __hip_bfloat162 v4 = h2[(size_t)i4 * 64 + l];
      __hip_bfloat162 v5 = h2[(size_t)i5 * 64 + l];
      __hip_bfloat162 v6 = h2[(size_t)i6 * 64 + l];
      __hip_bfloat162 v7 = h2[(size_t)i7 * 64 + l];
      s0 += __bfloat162float(v0.x) + __bfloat162float(v1.x);
      s1 += __bfloat162float(v0.y) + __bfloat162float(v1.y);
      t0 += __bfloat162float(v2.x) + __bfloat162float(v3.x);
      t1 += __bfloat162float(v2.y) + __bfloat162float(v3.y);
      s0 += __bfloat162float(v4.x) + __bfloat162float(v5.x);
      s1 += __bfloat162float(v4.y) + __bfloat162float(v5.y);
      t0 += __bfloat162float(v6.x) + __bfloat162float(v7.x);
      t1 += __bfloat162float(v6.y) + __bfloat162float(v7.y);
    }
    for (; j < dg; ++j) {
      int i0 = __builtin_amdgcn_readlane(myidx, j);
      __hip_bfloat162 v0 = h2[(size_t)i0 * 64 + l];
      s0 += __bfloat162float(v0.x);
      s1 += __bfloat162float(v0.y);
    }
    s0 += t0; s1 += t1;
    float rd = 1.0f / fmaxf((float)dgTrue, 1.0f);
    __hip_bfloat162 o;
    o.x = __float2bfloat16(s0 * rd);
    o.y = __float2bfloat16(s1 * rd);
    meanb[(size_t)node * 64 + l] = o;
  }
}

// ---------------- combine: out = x + normalize(elu(mean@Wl^T + bl + x@Wr^T)) ----------------
__global__ __launch_bounds__(256) void k_combine(
    const float* __restrict__ x, const short* __restrict__ Wlb,
    const float* __restrict__ bl, const short* __restrict__ Wrb,
    const unsigned short* __restrict__ meanb,
    float* __restrict__ out, int n)
{
  int tid = threadIdx.x;
  int l = tid & 63;
  int wid = (blockIdx.x * 256 + tid) >> 6;
  int row0 = wid * 16;
  if (row0 >= n) return;
  int lr = l & 15, kg = l >> 4;
  int rA = row0 + lr; if (rA > n - 1) rA = n - 1;

  f32x4 acc[8];
#pragma unroll
  for (int cb = 0; cb < 8; ++cb) {
    float bv = bl[16 * cb + lr];
    acc[cb] = (f32x4){bv, bv, bv, bv};
  }

  const unsigned short* mrow = meanb + (size_t)rA * DD;
#pragma unroll
  for (int ks = 0; ks < 4; ++ks) {
    int ko = 32 * ks + 8 * kg;
    bf16x8 a = *(const bf16x8*)(mrow + ko);
#pragma unroll
    for (int cb = 0; cb < 8; ++cb) {
      bf16x8 b = *(const bf16x8*)(Wlb + ((16 * cb + lr) * DD + ko));
      acc[cb] = __builtin_amdgcn_mfma_f32_16x16x32_bf16(a, b, acc[cb], 0, 0, 0);
    }
  }

  const float* xrow = x + (size_t)rA * DD;
#pragma unroll
  for (int ks = 0; ks < 4; ++ks) {
    int ko = 32 * ks + 8 * kg;
    float4 f0 = *(const float4*)(xrow + ko);
    float4 f1 = *(const float4*)(xrow + ko + 4);
    float fv[8] = {f0.x, f0.y, f0.z, f0.w, f1.x, f1.y, f1.z, f1.w};
    bf16x8 ah, al;
#pragma unroll
    for (int j = 0; j < 8; ++j) {
      short hb = bfbits(fv[j]);
      ah[j] = hb;
      al[j] = bfbits(fv[j] - bf2f(hb));
    }
#pragma unroll
    for (int cb = 0; cb < 8; ++cb) {
      bf16x8 b = *(const bf16x8*)(Wrb + ((16 * cb + lr) * DD + ko));
      acc[cb] = __builtin_amdgcn_mfma_f32_16x16x32_bf16(ah, b, acc[cb], 0, 0, 0);
      acc[cb] = __builtin_amdgcn_mfma_f32_16x16x32_bf16(al, b, acc[cb], 0, 0, 0);
    }
  }

  float ss[4] = {0.f, 0.f, 0.f, 0.f};
#pragma unroll
  for (int cb = 0; cb < 8; ++cb) {
#pragma unroll
    for (int i = 0; i < 4; ++i) {
      float z = acc[cb][i];
      z = z > 0.f ? z : expm1f(z);
      acc[cb][i] = z;
      ss[i] += z * z;
    }
  }
#pragma unroll
  for (int i = 0; i < 4; ++i) {
#pragma unroll
    for (int m = 1; m < 16; m <<= 1) ss[i] += __shfl_xor(ss[i], m);
  }
#pragma unroll
  for (int i = 0; i < 4; ++i) {
    int r = row0 + 4 * kg + i;
    if (r < n) {
      float inv = 1.f / fmaxf(sqrtf(ss[i]), EPSN);
#pragma unroll
      for (int cb = 0; cb < 8; ++cb) {
        int c = 16 * cb + lr;
        out[(size_t)r * DD + c] = x[(size_t)r * DD + c] + acc[cb][i] * inv;
      }
    }
  }
}

extern "C" void kernel_launch(void* const* d_in, const int* in_sizes, int n_in,
                              void* d_out, int out_size, void* d_ws, size_t ws_size,
                              hipStream_t stream) {
  const float* x  = (const float*)d_in[0];
  const int*   ei = (const int*)d_in[1];
  const float* Wp = (const float*)d_in[2];
  const float* bp = (const float*)d_in[3];
  const float* Wl = (const float*)d_in[4];
  const float* bl = (const float*)d_in[5];
  const float* Wr = (const float*)d_in[6];
  float* out = (float*)d_out;

  int n  = in_sizes[0] / DD;   // 50000
  int nE = in_sizes[1] / 2;    // 800000
  int m  = DD * DD;            // 16384
  int segCap = nE / 8 + 16384; // 116384 (55-sigma margin)
  unsigned scale = (unsigned)((((unsigned long long)8) << 32) / (unsigned long long)n);

  // ws layout (256B-aligned): h | meanb | cnt | cnt8 | slots | seg | Wb
  auto align256 = [](size_t v) { return (v + 255) & ~(size_t)255; };
  char* p = (char*)d_ws;
  unsigned short* h = (unsigned short*)p;      p += align256((size_t)n * DD * 2);
  unsigned short* meanb = (unsigned short*)p;  p += align256((size_t)n * DD * 2);
  int* cnt  = (int*)p;                         p += align256((size_t)n * 4);
  int* cnt8 = (int*)p;                         p += 256;
  unsigned short* slots = (unsigned short*)p;  p += align256((size_t)n * MAXDEG * 2);
  unsigned* seg = (unsigned*)p;                p += align256((size_t)8 * segCap * 4);
  short* Wb = (short*)p;                       p += align256((size_t)3 * m * 2);
  short* Wpb = Wb, *Wlb = Wb + m, *Wrb = Wb + 2 * m;

  k_init<<<256, 256, 0, stream>>>(Wp, Wl, Wr, Wb, m, cnt, cnt8, n);

  int nWaves   = (n + 15) / 16;                 // 3125
  int nProjBlk = (nWaves + 3) / 4;              // 782
  int nABlk    = (nE + EPB - 1) / EPB;          // 391
  k_projA<<<nABlk + nProjBlk, 256, 0, stream>>>(
      x, Wpb, bp, h, ei, seg, cnt8, n, nE, nABlk, scale, segCap);

  int nChunkB = (segCap + EPB - 1) / EPB;       // 57
  k_passB<<<8 * nChunkB, 256, 0, stream>>>(seg, cnt8, cnt, slots, segCap);

  int nGWaves = (n + 3) / 4;                    // 12500
  int nGBlk   = (nGWaves + 3) / 4;              // 3125
  k_gather<<<nGBlk, 256, 0, stream>>>(
      cnt, slots, (const __hip_bfloat162*)h, (__hip_bfloat162*)meanb, n);

  k_combine<<<nProjBlk, 256, 0, stream>>>(x, Wlb, bl, Wrb, meanb, out, n);
}

// Round 8
// 130.182 us; speedup vs baseline: 1.1499x; 1.1499x over previous
//
#include <hip/hip_runtime.h>
#include <hip/hip_bf16.h>

#define DD 128
#define EPSN 1e-12f
#define MAXDEG 64
#define EPB 2048        // edges per block (256 thr x 8) for passA/passB

typedef __attribute__((ext_vector_type(8))) short bf16x8;
typedef __attribute__((ext_vector_type(4))) float f32x4;

__device__ __forceinline__ short bfbits(float f) {
  unsigned u = __float_as_uint(f);
  u += 0x7FFF + ((u >> 16) & 1);  // round-to-nearest-even
  return (short)(u >> 16);
}
__device__ __forceinline__ float bf2f(short s) {
  return __uint_as_float(((unsigned)(unsigned short)s) << 16);
}

// ---------------- init: cvt W to bf16 + zero cnt/cnt8 ----------------
__global__ __launch_bounds__(256) void k_init(
    const float* __restrict__ Wp, const float* __restrict__ Wl,
    const float* __restrict__ Wr, short* __restrict__ Wb, int m,
    int* __restrict__ cnt, int* __restrict__ cnt8, int n)
{
  int i = blockIdx.x * 256 + threadIdx.x;
  if (i < m) {
    Wb[i]         = bfbits(Wp[i]);
    Wb[m + i]     = bfbits(Wl[i]);
    Wb[2 * m + i] = bfbits(Wr[i]);
  }
  if (i < n) cnt[i] = 0;
  if (i < 8) cnt8[i] = 0;
}

// ---------------- fused: passA (radix-partition edges) ∥ project ----------------
__global__ __launch_bounds__(256) void k_projA(
    const float* __restrict__ x, const short* __restrict__ Wpb,
    const float* __restrict__ bp, unsigned short* __restrict__ h,
    const int* __restrict__ ei, unsigned* __restrict__ seg,
    int* __restrict__ cnt8, int n, int nE, int nABlk,
    unsigned scale, int segCap)
{
  int b = blockIdx.x;
  int tid = threadIdx.x;

  if (b < nABlk) {
    // ---- passA: bin 2048 edges by dst range, write packed (d<<16)|s ----
    __shared__ int bcnt[8];
    __shared__ int bcur[8];
    if (tid < 8) bcnt[tid] = 0;
    __syncthreads();
    int base = b * EPB;
    int dv[8], sv[8], bv[8];
    bool val[8];
#pragma unroll
    for (int u = 0; u < 8; ++u) {
      int e = base + u * 256 + tid;
      val[u] = (e < nE);
      if (val[u]) {
        dv[u] = ei[nE + e];
        sv[u] = ei[e];
        bv[u] = (int)(((unsigned long long)(unsigned)dv[u] * scale) >> 32);
        atomicAdd(&bcnt[bv[u]], 1);
      }
    }
    __syncthreads();
    if (tid < 8) bcur[tid] = atomicAdd(&cnt8[tid], bcnt[tid]);
    __syncthreads();
#pragma unroll
    for (int u = 0; u < 8; ++u) {
      if (val[u]) {
        int pos = atomicAdd(&bcur[bv[u]], 1);
        if (pos < segCap)
          seg[(size_t)bv[u] * segCap + pos] =
              ((unsigned)dv[u] << 16) | (unsigned)sv[u];
      }
    }
    return;
  }

  // ---- project: h = relu(x @ Wp^T + bp), split-bf16 x, MFMA ----
  int l = tid & 63;
  int wid = ((b - nABlk) * 256 + tid) >> 6;
  int row0 = wid * 16;
  if (row0 >= n) return;
  int lr = l & 15, kg = l >> 4;
  int rA = row0 + lr; if (rA > n - 1) rA = n - 1;

  f32x4 acc[8];
#pragma unroll
  for (int cb = 0; cb < 8; ++cb) {
    float bv2 = bp[16 * cb + lr];
    acc[cb] = (f32x4){bv2, bv2, bv2, bv2};
  }

  const float* xrow = x + (size_t)rA * DD;
#pragma unroll
  for (int ks = 0; ks < 4; ++ks) {
    int ko = 32 * ks + 8 * kg;
    float4 f0 = *(const float4*)(xrow + ko);
    float4 f1 = *(const float4*)(xrow + ko + 4);
    float fv[8] = {f0.x, f0.y, f0.z, f0.w, f1.x, f1.y, f1.z, f1.w};
    bf16x8 ah, al;
#pragma unroll
    for (int j = 0; j < 8; ++j) {
      short hb = bfbits(fv[j]);
      ah[j] = hb;
      al[j] = bfbits(fv[j] - bf2f(hb));
    }
#pragma unroll
    for (int cb = 0; cb < 8; ++cb) {
      bf16x8 bfr = *(const bf16x8*)(Wpb + ((16 * cb + lr) * DD + ko));
      acc[cb] = __builtin_amdgcn_mfma_f32_16x16x32_bf16(ah, bfr, acc[cb], 0, 0, 0);
      acc[cb] = __builtin_amdgcn_mfma_f32_16x16x32_bf16(al, bfr, acc[cb], 0, 0, 0);
    }
  }

#pragma unroll
  for (int i = 0; i < 4; ++i) {
    int r = row0 + 4 * kg + i;
    if (r < n) {
#pragma unroll
      for (int cb = 0; cb < 8; ++cb) {
        float v = fmaxf(acc[cb][i], 0.f);
        h[(size_t)r * DD + 16 * cb + lr] = (unsigned short)bfbits(v);
      }
    }
  }
}

// ---------------- passB: L2-resident scatter into slot buckets ----------------
__global__ __launch_bounds__(256) void k_passB(
    const unsigned* __restrict__ seg, const int* __restrict__ cnt8,
    int* __restrict__ cnt, unsigned short* __restrict__ slots, int segCap)
{
  int b = blockIdx.x;
  int tid = threadIdx.x;
  int r = b & 7;
  int chunk = b >> 3;
  int len = cnt8[r]; if (len > segCap) len = segCap;
  const unsigned* s = seg + (size_t)r * segCap;
  int base = chunk * EPB;
#pragma unroll
  for (int u = 0; u < 8; ++u) {
    int e = base + u * 256 + tid;
    if (e < len) {
      unsigned p = s[e];
      int d = (int)(p >> 16);
      int src = (int)(p & 0xFFFFu);
      int pos = atomicAdd(&cnt[d], 1);
      if (pos < MAXDEG) slots[(size_t)d * MAXDEG + pos] = (unsigned short)src;
    }
  }
}

// ---------------- gather-reduce: 4 nodes per wave ----------------
__global__ __launch_bounds__(256) void k_gather(
    const int* __restrict__ cnt, const unsigned short* __restrict__ slots,
    const __hip_bfloat162* __restrict__ h2,
    __hip_bfloat162* __restrict__ meanb, int n)
{
  int w = (blockIdx.x * 256 + threadIdx.x) >> 6;
  int l = threadIdx.x & 63;
  int node0 = w * 4;
  if (node0 >= n) return;

#pragma unroll 1
  for (int i = 0; i < 4; ++i) {
    int node = node0 + i;
    if (node >= n) break;
    int dgTrue = cnt[node];
    int dg = dgTrue < MAXDEG ? dgTrue : MAXDEG;
    int myidx = (int)slots[(size_t)node * MAXDEG + l];

    float s0 = 0.f, s1 = 0.f, t0 = 0.f, t1 = 0.f;
    int j = 0;
    for (; j + 8 <= dg; j += 8) {
      int i0 = __builtin_amdgcn_readlane(myidx, j);
      int i1 = __builtin_amdgcn_readlane(myidx, j + 1);
      int i2 = __builtin_amdgcn_readlane(myidx, j + 2);
      int i3 = __builtin_amdgcn_readlane(myidx, j + 3);
      int i4 = __builtin_amdgcn_readlane(myidx, j + 4);
      int i5 = __builtin_amdgcn_readlane(myidx, j + 5);
      int i6 = __builtin_amdgcn_readlane(myidx, j + 6);
      int i7 = __builtin_amdgcn_readlane(myidx, j + 7);
      __hip_bfloat162 v0 = h2[(size_t)i0 * 64 + l];
      __hip_bfloat162 v1 = h2[(size_t)i1 * 64 + l];
      __hip_bfloat162 v2 = h2[(size_t)i2 * 64 + l];
      __hip_bfloat162 v3 = h2[(size_t)i3 * 64 + l];
      __hip_bfloat162 v4 = h2[(size_t)i4 * 64 + l];
      __hip_bfloat162 v5 = h2[(size_t)i5 * 64 + l];
      __hip_bfloat162 v6 = h2[(size_t)i6 * 64 + l];
      __hip_bfloat162 v7 = h2[(size_t)i7 * 64 + l];
      s0 += __bfloat162float(v0.x) + __bfloat162float(v1.x);
      s1 += __bfloat162float(v0.y) + __bfloat162float(v1.y);
      t0 += __bfloat162float(v2.x) + __bfloat162float(v3.x);
      t1 += __bfloat162float(v2.y) + __bfloat162float(v3.y);
      s0 += __bfloat162float(v4.x) + __bfloat162float(v5.x);
      s1 += __bfloat162float(v4.y) + __bfloat162float(v5.y);
      t0 += __bfloat162float(v6.x) + __bfloat162float(v7.x);
      t1 += __bfloat162float(v6.y) + __bfloat162float(v7.y);
    }
    for (; j < dg; ++j) {
      int i0 = __builtin_amdgcn_readlane(myidx, j);
      __hip_bfloat162 v0 = h2[(size_t)i0 * 64 + l];
      s0 += __bfloat162float(v0.x);
      s1 += __bfloat162float(v0.y);
    }
    s0 += t0; s1 += t1;
    float rd = 1.0f / fmaxf((float)dgTrue, 1.0f);
    __hip_bfloat162 o;
    o.x = __float2bfloat16(s0 * rd);
    o.y = __float2bfloat16(s1 * rd);
    meanb[(size_t)node * 64 + l] = o;
  }
}

// ---------------- combine v2: 512 thr, W in LDS (swizzled), col-split waves ----------------
// wave pair (2 waves) per 16-row group: half 0 -> cols 0..63, half 1 -> cols 64..127.
// Row L2-norm completed via small LDS exchange between the pair.
__global__ __launch_bounds__(512) void k_combine(
    const float* __restrict__ x, const short* __restrict__ Wlb,
    const float* __restrict__ bl, const short* __restrict__ Wrb,
    const unsigned short* __restrict__ meanb,
    float* __restrict__ out, int n)
{
  __shared__ uint4 Wu[4096];       // 64KB: [mat][row][unit (j ^ (row&15))]
  __shared__ float ssh[4 * 32];    // [rg][half][16 rows]

  int tid = threadIdx.x;

  // stage Wl (mat 0) + Wr (mat 1), 16B units, XOR-swizzled within each row
  const uint4* gl = (const uint4*)Wlb;
  const uint4* gr = (const uint4*)Wrb;
#pragma unroll
  for (int it = 0; it < 8; ++it) {
    int g = it * 512 + tid;
    int mat = g >> 11;
    int rem = g & 2047;
    int row = rem >> 4, j = rem & 15;
    uint4 v = mat ? gr[rem] : gl[rem];
    Wu[(mat << 11) | (row << 4) | (j ^ (row & 15))] = v;
  }
  __syncthreads();

  int l = tid & 63;
  int wv = tid >> 6;        // 0..7
  int rg = wv >> 1;         // 0..3
  int half = wv & 1;        // 0..1
  int row0 = (blockIdx.x * 4 + rg) * 16;
  int lr = l & 15, kg = l >> 4;
  bool active = (row0 < n);

  f32x4 acc[4];
  float ss[4] = {0.f, 0.f, 0.f, 0.f};

  if (active) {
    int rA = row0 + lr; if (rA > n - 1) rA = n - 1;
#pragma unroll
    for (int q = 0; q < 4; ++q) {
      float bv = bl[16 * (4 * half + q) + lr];
      acc[q] = (f32x4){bv, bv, bv, bv};
    }

    const unsigned short* mrow = meanb + (size_t)rA * DD;
    const float* xrow = x + (size_t)rA * DD;
#pragma unroll
    for (int ks = 0; ks < 4; ++ks) {
      int ko = 32 * ks + 8 * kg;
      bf16x8 a = *(const bf16x8*)(mrow + ko);
      float4 f0 = *(const float4*)(xrow + ko);
      float4 f1 = *(const float4*)(xrow + ko + 4);
      float fv[8] = {f0.x, f0.y, f0.z, f0.w, f1.x, f1.y, f1.z, f1.w};
      bf16x8 ah, al;
#pragma unroll
      for (int jj = 0; jj < 8; ++jj) {
        short hb = bfbits(fv[jj]);
        ah[jj] = hb;
        al[jj] = bfbits(fv[jj] - bf2f(hb));
      }
      int ju = 4 * ks + kg;
#pragma unroll
      for (int q = 0; q < 4; ++q) {
        int row = 16 * (4 * half + q) + lr;
        bf16x8 bL = *(const bf16x8*)&Wu[(0 << 11) | (row << 4) | (ju ^ lr)];
        bf16x8 bR = *(const bf16x8*)&Wu[(1 << 11) | (row << 4) | (ju ^ lr)];
        acc[q] = __builtin_amdgcn_mfma_f32_16x16x32_bf16(a,  bL, acc[q], 0, 0, 0);
        acc[q] = __builtin_amdgcn_mfma_f32_16x16x32_bf16(ah, bR, acc[q], 0, 0, 0);
        acc[q] = __builtin_amdgcn_mfma_f32_16x16x32_bf16(al, bR, acc[q], 0, 0, 0);
      }
    }

    // ELU + partial row-norm (this wave's 64 cols)
#pragma unroll
    for (int q = 0; q < 4; ++q) {
#pragma unroll
      for (int i = 0; i < 4; ++i) {
        float z = acc[q][i];
        z = z > 0.f ? z : expm1f(z);
        acc[q][i] = z;
        ss[i] += z * z;
      }
    }
#pragma unroll
    for (int i = 0; i < 4; ++i) {
#pragma unroll
      for (int m2 = 1; m2 < 16; m2 <<= 1) ss[i] += __shfl_xor(ss[i], m2);
    }
    if (lr == 0) {
#pragma unroll
      for (int i = 0; i < 4; ++i) ssh[rg * 32 + half * 16 + 4 * kg + i] = ss[i];
    }
  }
  __syncthreads();

  if (active) {
#pragma unroll
    for (int i = 0; i < 4; ++i) {
      int r = row0 + 4 * kg + i;
      if (r < n) {
        float tot = ssh[rg * 32 + 4 * kg + i] + ssh[rg * 32 + 16 + 4 * kg + i];
        float inv = 1.f / fmaxf(sqrtf(tot), EPSN);
#pragma unroll
        for (int q = 0; q < 4; ++q) {
          int c = 16 * (4 * half + q) + lr;
          out[(size_t)r * DD + c] = x[(size_t)r * DD + c] + acc[q][i] * inv;
        }
      }
    }
  }
}

extern "C" void kernel_launch(void* const* d_in, const int* in_sizes, int n_in,
                              void* d_out, int out_size, void* d_ws, size_t ws_size,
                              hipStream_t stream) {
  const float* x  = (const float*)d_in[0];
  const int*   ei = (const int*)d_in[1];
  const float* Wp = (const float*)d_in[2];
  const float* bp = (const float*)d_in[3];
  const float* Wl = (const float*)d_in[4];
  const float* bl = (const float*)d_in[5];
  const float* Wr = (const float*)d_in[6];
  float* out = (float*)d_out;

  int n  = in_sizes[0] / DD;   // 50000
  int nE = in_sizes[1] / 2;    // 800000
  int m  = DD * DD;            // 16384
  int segCap = nE / 8 + 16384; // 116384 (55-sigma margin)
  unsigned scale = (unsigned)((((unsigned long long)8) << 32) / (unsigned long long)n);

  // ws layout (256B-aligned): h | meanb | cnt | cnt8 | slots | seg | Wb
  auto align256 = [](size_t v) { return (v + 255) & ~(size_t)255; };
  char* p = (char*)d_ws;
  unsigned short* h = (unsigned short*)p;      p += align256((size_t)n * DD * 2);
  unsigned short* meanb = (unsigned short*)p;  p += align256((size_t)n * DD * 2);
  int* cnt  = (int*)p;                         p += align256((size_t)n * 4);
  int* cnt8 = (int*)p;                         p += 256;
  unsigned short* slots = (unsigned short*)p;  p += align256((size_t)n * MAXDEG * 2);
  unsigned* seg = (unsigned*)p;                p += align256((size_t)8 * segCap * 4);
  short* Wb = (short*)p;                       p += align256((size_t)3 * m * 2);
  short* Wpb = Wb, *Wlb = Wb + m, *Wrb = Wb + 2 * m;

  k_init<<<256, 256, 0, stream>>>(Wp, Wl, Wr, Wb, m, cnt, cnt8, n);

  int nWaves   = (n + 15) / 16;                 // 3125
  int nProjBlk = (nWaves + 3) / 4;              // 782
  int nABlk    = (nE + EPB - 1) / EPB;          // 391
  k_projA<<<nABlk + nProjBlk, 256, 0, stream>>>(
      x, Wpb, bp, h, ei, seg, cnt8, n, nE, nABlk, scale, segCap);

  int nChunkB = (segCap + EPB - 1) / EPB;       // 57
  k_passB<<<8 * nChunkB, 256, 0, stream>>>(seg, cnt8, cnt, slots, segCap);

  int nGWaves = (n + 3) / 4;                    // 12500
  int nGBlk   = (nGWaves + 3) / 4;              // 3125
  k_gather<<<nGBlk, 256, 0, stream>>>(
      cnt, slots, (const __hip_bfloat162*)h, (__hip_bfloat162*)meanb, n);

  int nCombBlk = (nWaves + 3) / 4;              // 782 (4 row-groups x 2 halves = 8 waves)
  k_combine<<<nCombBlk, 512, 0, stream>>>(x, Wlb, bl, Wrb, meanb, out, n);
}

// Round 9
// 122.319 us; speedup vs baseline: 1.2238x; 1.0643x over previous
//
#include <hip/hip_runtime.h>
#include <hip/hip_bf16.h>

#define DD 128
#define EPSN 1e-12f
#define MAXDEG 64
#define EPB_A 4096      // edges per passA block (512 thr x 8)
#define EPB_B 2048      // edges per passB block (256 thr x 8)

typedef __attribute__((ext_vector_type(8))) short bf16x8;
typedef __attribute__((ext_vector_type(4))) float f32x4;

__device__ __forceinline__ short bfbits(float f) {
  unsigned u = __float_as_uint(f);
  u += 0x7FFF + ((u >> 16) & 1);  // round-to-nearest-even
  return (short)(u >> 16);
}
__device__ __forceinline__ float bf2f(short s) {
  return __uint_as_float(((unsigned)(unsigned short)s) << 16);
}
__device__ __forceinline__ unsigned packbf(float a, float b) {
  return (unsigned)(unsigned short)bfbits(a) |
         ((unsigned)(unsigned short)bfbits(b) << 16);
}

// ---------------- K1: passA (radix-partition edges, zero cnt) ∥ project ----------------
// project stages Wp f32 -> bf16 swizzled LDS; 8 waves x 16 rows per block.
__global__ __launch_bounds__(512) void k_projA(
    const float* __restrict__ x, const float* __restrict__ Wp,
    const float* __restrict__ bp, unsigned short* __restrict__ h,
    const int* __restrict__ ei, unsigned* __restrict__ seg,
    int* __restrict__ cnt8, int* __restrict__ cnt,
    int n, int nE, int nABlk, unsigned scale, int segCap)
{
  __shared__ uint4 WuP[2048];   // 32KB: [row][unit (j ^ (row&15))], 16B units
  int b = blockIdx.x;
  int tid = threadIdx.x;

  if (b < nABlk) {
    // ---- passA: bin 4096 edges by dst range, write packed (d<<16)|s ----
    int* bcnt = (int*)&WuP[0];
    int* bcur = bcnt + 8;
    if (tid < 8) bcnt[tid] = 0;
    int zi = b * 256 + tid;                 // fold cnt zeroing in
    if (tid < 256 && zi < n) cnt[zi] = 0;
    __syncthreads();
    int base = b * EPB_A;
    int dv[8], sv[8], bv[8];
    bool val[8];
#pragma unroll
    for (int u = 0; u < 8; ++u) {
      int e = base + u * 512 + tid;
      val[u] = (e < nE);
      if (val[u]) {
        dv[u] = ei[nE + e];
        sv[u] = ei[e];
        bv[u] = (int)(((unsigned long long)(unsigned)dv[u] * scale) >> 32);
        atomicAdd(&bcnt[bv[u]], 1);
      }
    }
    __syncthreads();
    if (tid < 8) bcur[tid] = atomicAdd(&cnt8[tid], bcnt[tid]);
    __syncthreads();
#pragma unroll
    for (int u = 0; u < 8; ++u) {
      if (val[u]) {
        int pos = atomicAdd(&bcur[bv[u]], 1);
        if (pos < segCap)
          seg[(size_t)bv[u] * segCap + pos] =
              ((unsigned)dv[u] << 16) | (unsigned)sv[u];
      }
    }
    return;
  }

  // ---- project: stage Wp (f32 -> bf16, swizzled) ----
#pragma unroll
  for (int it = 0; it < 4; ++it) {
    int g = it * 512 + tid;          // unit 0..2047
    int row = g >> 4, j = g & 15;
    const float* src = Wp + row * DD + j * 8;
    float4 f0 = *(const float4*)src;
    float4 f1 = *(const float4*)(src + 4);
    uint4 v;
    v.x = packbf(f0.x, f0.y); v.y = packbf(f0.z, f0.w);
    v.z = packbf(f1.x, f1.y); v.w = packbf(f1.z, f1.w);
    WuP[(row << 4) | (j ^ (row & 15))] = v;
  }
  __syncthreads();

  int l = tid & 63;
  int wv = tid >> 6;
  int row0 = ((b - nABlk) * 8 + wv) * 16;
  if (row0 >= n) return;
  int lr = l & 15, kg = l >> 4;
  int rA = row0 + lr; if (rA > n - 1) rA = n - 1;

  f32x4 acc[8];
#pragma unroll
  for (int cb = 0; cb < 8; ++cb) {
    float bv2 = bp[16 * cb + lr];
    acc[cb] = (f32x4){bv2, bv2, bv2, bv2};
  }

  const float* xrow = x + (size_t)rA * DD;
#pragma unroll
  for (int ks = 0; ks < 4; ++ks) {
    int ko = 32 * ks + 8 * kg;
    float4 f0 = *(const float4*)(xrow + ko);
    float4 f1 = *(const float4*)(xrow + ko + 4);
    float fv[8] = {f0.x, f0.y, f0.z, f0.w, f1.x, f1.y, f1.z, f1.w};
    bf16x8 ah, al;
#pragma unroll
    for (int j = 0; j < 8; ++j) {
      short hb = bfbits(fv[j]);
      ah[j] = hb;
      al[j] = bfbits(fv[j] - bf2f(hb));
    }
    int ju = 4 * ks + kg;
#pragma unroll
    for (int cb = 0; cb < 8; ++cb) {
      int row = 16 * cb + lr;
      bf16x8 bfr = *(const bf16x8*)&WuP[(row << 4) | (ju ^ lr)];
      acc[cb] = __builtin_amdgcn_mfma_f32_16x16x32_bf16(ah, bfr, acc[cb], 0, 0, 0);
      acc[cb] = __builtin_amdgcn_mfma_f32_16x16x32_bf16(al, bfr, acc[cb], 0, 0, 0);
    }
  }

#pragma unroll
  for (int i = 0; i < 4; ++i) {
    int r = row0 + 4 * kg + i;
    if (r < n) {
#pragma unroll
      for (int cb = 0; cb < 8; ++cb) {
        float v = fmaxf(acc[cb][i], 0.f);
        h[(size_t)r * DD + 16 * cb + lr] = (unsigned short)bfbits(v);
      }
    }
  }
}

// ---------------- K2: passB — L2-resident scatter into slot buckets ----------------
__global__ __launch_bounds__(256) void k_passB(
    const unsigned* __restrict__ seg, const int* __restrict__ cnt8,
    int* __restrict__ cnt, unsigned short* __restrict__ slots, int segCap)
{
  int b = blockIdx.x;
  int tid = threadIdx.x;
  int r = b & 7;
  int chunk = b >> 3;
  int len = cnt8[r]; if (len > segCap) len = segCap;
  const unsigned* s = seg + (size_t)r * segCap;
  int base = chunk * EPB_B;
#pragma unroll
  for (int u = 0; u < 8; ++u) {
    int e = base + u * 256 + tid;
    if (e < len) {
      unsigned p = s[e];
      int d = (int)(p >> 16);
      int src = (int)(p & 0xFFFFu);
      int pos = atomicAdd(&cnt[d], 1);
      if (pos < MAXDEG) slots[(size_t)d * MAXDEG + pos] = (unsigned short)src;
    }
  }
}

// ---------------- K3: fused gather (8 nodes/wave -> LDS) + col-split MFMA combine ----------------
// 512 thr = 8 waves: 4 row-groups x 2 col-halves. LDS = 64KB W + 16KB means = 80KB.
__global__ __launch_bounds__(512) void k_gcomb(
    const float* __restrict__ x, const float* __restrict__ Wl,
    const float* __restrict__ bl, const float* __restrict__ Wr,
    const int* __restrict__ cnt, const unsigned short* __restrict__ slots,
    const __hip_bfloat162* __restrict__ h2,
    float* __restrict__ out, int n)
{
  __shared__ uint4 Wu[4096];      // 64KB: [mat][row][unit (j ^ (row&15))]
  __shared__ unsigned mw[4096];   // 16KB: means [rg][16 rows][64 words, swizzled]
  int tid = threadIdx.x;

  // ---- stage Wl (mat 0) + Wr (mat 1) from f32, swizzled ----
#pragma unroll
  for (int it = 0; it < 8; ++it) {
    int g = it * 512 + tid;       // 0..4095
    int mat = g >> 11, rem = g & 2047;
    int row = rem >> 4, j = rem & 15;
    const float* src = (mat ? Wr : Wl) + row * DD + j * 8;
    float4 f0 = *(const float4*)src;
    float4 f1 = *(const float4*)(src + 4);
    uint4 v;
    v.x = packbf(f0.x, f0.y); v.y = packbf(f0.z, f0.w);
    v.z = packbf(f1.x, f1.y); v.w = packbf(f1.z, f1.w);
    Wu[(mat << 11) | (row << 4) | (j ^ (row & 15))] = v;
  }

  int l = tid & 63;
  int wv = tid >> 6;        // 0..7
  int rg = wv >> 1;         // 0..3
  int half = wv & 1;        // 0..1
  int row0 = (blockIdx.x * 4 + rg) * 16;
  int lr = l & 15, kg = l >> 4;
  bool active = (row0 < n);

  // ---- gather: this wave's 8 nodes -> swizzled means tile ----
#pragma unroll 1
  for (int i = 0; i < 8; ++i) {
    int r = half * 8 + i;           // 0..15 within row-group
    int node = row0 + r;
    unsigned word = 0;
    if (node < n) {
      int dgTrue = cnt[node];
      int dg = dgTrue < MAXDEG ? dgTrue : MAXDEG;
      int myidx = (int)slots[(size_t)node * MAXDEG + l];
      float s0 = 0.f, s1 = 0.f, t0 = 0.f, t1 = 0.f;
      int j = 0;
      for (; j + 8 <= dg; j += 8) {
        int i0 = __builtin_amdgcn_readlane(myidx, j);
        int i1 = __builtin_amdgcn_readlane(myidx, j + 1);
        int i2 = __builtin_amdgcn_readlane(myidx, j + 2);
        int i3 = __builtin_amdgcn_readlane(myidx, j + 3);
        int i4 = __builtin_amdgcn_readlane(myidx, j + 4);
        int i5 = __builtin_amdgcn_readlane(myidx, j + 5);
        int i6 = __builtin_amdgcn_readlane(myidx, j + 6);
        int i7 = __builtin_amdgcn_readlane(myidx, j + 7);
        __hip_bfloat162 v0 = h2[(size_t)i0 * 64 + l];
        __hip_bfloat162 v1 = h2[(size_t)i1 * 64 + l];
        __hip_bfloat162 v2 = h2[(size_t)i2 * 64 + l];
        __hip_bfloat162 v3 = h2[(size_t)i3 * 64 + l];
        __hip_bfloat162 v4 = h2[(size_t)i4 * 64 + l];
        __hip_bfloat162 v5 = h2[(size_t)i5 * 64 + l];
        __hip_bfloat162 v6 = h2[(size_t)i6 * 64 + l];
        __hip_bfloat162 v7 = h2[(size_t)i7 * 64 + l];
        s0 += __bfloat162float(v0.x) + __bfloat162float(v1.x);
        s1 += __bfloat162float(v0.y) + __bfloat162float(v1.y);
        t0 += __bfloat162float(v2.x) + __bfloat162float(v3.x);
        t1 += __bfloat162float(v2.y) + __bfloat162float(v3.y);
        s0 += __bfloat162float(v4.x) + __bfloat162float(v5.x);
        s1 += __bfloat162float(v4.y) + __bfloat162float(v5.y);
        t0 += __bfloat162float(v6.x) + __bfloat162float(v7.x);
        t1 += __bfloat162float(v6.y) + __bfloat162float(v7.y);
      }
      for (; j < dg; ++j) {
        int i0 = __builtin_amdgcn_readlane(myidx, j);
        __hip_bfloat162 v0 = h2[(size_t)i0 * 64 + l];
        s0 += __bfloat162float(v0.x);
        s1 += __bfloat162float(v0.y);
      }
      s0 += t0; s1 += t1;
      float rd = 1.0f / fmaxf((float)dgTrue, 1.0f);
      word = packbf(s0 * rd, s1 * rd);
    }
    // lane l holds words (elements 2l,2l+1); swizzle word units for MFMA read
    mw[rg * 1024 + r * 64 + (((l >> 2) ^ (r & 15)) << 2) + (l & 3)] = word;
  }
  __syncthreads();   // W staged + means visible

  f32x4 acc[4];
  float ss[4] = {0.f, 0.f, 0.f, 0.f};

  if (active) {
    int rA = row0 + lr; if (rA > n - 1) rA = n - 1;
#pragma unroll
    for (int q = 0; q < 4; ++q) {
      float bv = bl[16 * (4 * half + q) + lr];
      acc[q] = (f32x4){bv, bv, bv, bv};
    }

    const uint4* mw4 = (const uint4*)mw;
    const float* xrow = x + (size_t)rA * DD;
#pragma unroll
    for (int ks = 0; ks < 4; ++ks) {
      int ko = 32 * ks + 8 * kg;
      int ju = 4 * ks + kg;
      bf16x8 a = *(const bf16x8*)&mw4[rg * 256 + lr * 16 + (ju ^ lr)];
      float4 f0 = *(const float4*)(xrow + ko);
      float4 f1 = *(const float4*)(xrow + ko + 4);
      float fv[8] = {f0.x, f0.y, f0.z, f0.w, f1.x, f1.y, f1.z, f1.w};
      bf16x8 ah, al;
#pragma unroll
      for (int jj = 0; jj < 8; ++jj) {
        short hb = bfbits(fv[jj]);
        ah[jj] = hb;
        al[jj] = bfbits(fv[jj] - bf2f(hb));
      }
#pragma unroll
      for (int q = 0; q < 4; ++q) {
        int row = 16 * (4 * half + q) + lr;
        bf16x8 bL = *(const bf16x8*)&Wu[(0 << 11) | (row << 4) | (ju ^ lr)];
        bf16x8 bR = *(const bf16x8*)&Wu[(1 << 11) | (row << 4) | (ju ^ lr)];
        acc[q] = __builtin_amdgcn_mfma_f32_16x16x32_bf16(a,  bL, acc[q], 0, 0, 0);
        acc[q] = __builtin_amdgcn_mfma_f32_16x16x32_bf16(ah, bR, acc[q], 0, 0, 0);
        acc[q] = __builtin_amdgcn_mfma_f32_16x16x32_bf16(al, bR, acc[q], 0, 0, 0);
      }
    }

    // ELU + partial row-norm (this wave's 64 cols)
#pragma unroll
    for (int q = 0; q < 4; ++q) {
#pragma unroll
      for (int i = 0; i < 4; ++i) {
        float z = acc[q][i];
        z = z > 0.f ? z : expm1f(z);
        acc[q][i] = z;
        ss[i] += z * z;
      }
    }
#pragma unroll
    for (int i = 0; i < 4; ++i) {
#pragma unroll
      for (int m2 = 1; m2 < 16; m2 <<= 1) ss[i] += __shfl_xor(ss[i], m2);
    }
  }
  __syncthreads();   // all means reads done; safe to alias ssh onto mw

  float* ssh = (float*)mw;
  if (active && lr == 0) {
#pragma unroll
    for (int i = 0; i < 4; ++i) ssh[rg * 32 + half * 16 + 4 * kg + i] = ss[i];
  }
  __syncthreads();

  if (active) {
#pragma unroll
    for (int i = 0; i < 4; ++i) {
      int r = row0 + 4 * kg + i;
      if (r < n) {
        float tot = ssh[rg * 32 + 4 * kg + i] + ssh[rg * 32 + 16 + 4 * kg + i];
        float inv = 1.f / fmaxf(sqrtf(tot), EPSN);
#pragma unroll
        for (int q = 0; q < 4; ++q) {
          int c = 16 * (4 * half + q) + lr;
          out[(size_t)r * DD + c] = x[(size_t)r * DD + c] + acc[q][i] * inv;
        }
      }
    }
  }
}

extern "C" void kernel_launch(void* const* d_in, const int* in_sizes, int n_in,
                              void* d_out, int out_size, void* d_ws, size_t ws_size,
                              hipStream_t stream) {
  const float* x  = (const float*)d_in[0];
  const int*   ei = (const int*)d_in[1];
  const float* Wp = (const float*)d_in[2];
  const float* bp = (const float*)d_in[3];
  const float* Wl = (const float*)d_in[4];
  const float* bl = (const float*)d_in[5];
  const float* Wr = (const float*)d_in[6];
  float* out = (float*)d_out;

  int n  = in_sizes[0] / DD;   // 50000
  int nE = in_sizes[1] / 2;    // 800000
  int segCap = nE / 8 + 16384; // 116384 (55-sigma margin)
  unsigned scale = (unsigned)((((unsigned long long)8) << 32) / (unsigned long long)n);

  // ws layout (256B-aligned): h | cnt | cnt8 | slots | seg
  auto align256 = [](size_t v) { return (v + 255) & ~(size_t)255; };
  char* p = (char*)d_ws;
  unsigned short* h = (unsigned short*)p;      p += align256((size_t)n * DD * 2);
  int* cnt  = (int*)p;                         p += align256((size_t)n * 4);
  int* cnt8 = (int*)p;                         p += 256;
  unsigned short* slots = (unsigned short*)p;  p += align256((size_t)n * MAXDEG * 2);
  unsigned* seg = (unsigned*)p;                p += align256((size_t)8 * segCap * 4);

  hipMemsetAsync(cnt8, 0, 256, stream);

  int nABlk = (nE + EPB_A - 1) / EPB_A;         // 196
  int nPBlk = (n + 127) / 128;                  // 391
  k_projA<<<nABlk + nPBlk, 512, 0, stream>>>(
      x, Wp, bp, h, ei, seg, cnt8, cnt, n, nE, nABlk, scale, segCap);

  int nChunkB = (segCap + EPB_B - 1) / EPB_B;   // 57
  k_passB<<<8 * nChunkB, 256, 0, stream>>>(seg, cnt8, cnt, slots, segCap);

  int nCBlk = (n + 63) / 64;                    // 782
  k_gcomb<<<nCBlk, 512, 0, stream>>>(
      x, Wl, bl, Wr, cnt, slots, (const __hip_bfloat162*)h, out, n);
}

// Round 10
// 112.862 us; speedup vs baseline: 1.3264x; 1.0838x over previous
//
#include <hip/hip_runtime.h>
#include <hip/hip_bf16.h>

#define DD 128
#define EPSN 1e-12f
#define MAXDEG 64
#define EPB_A 4096      // edges per passA block (512 thr x 8)
#define EPB_B 2048      // edges per passB block (256 thr x 8)

typedef __attribute__((ext_vector_type(8))) short bf16x8;
typedef __attribute__((ext_vector_type(4))) float f32x4;

__device__ __forceinline__ short bfbits(float f) {
  unsigned u = __float_as_uint(f);
  u += 0x7FFF + ((u >> 16) & 1);  // round-to-nearest-even
  return (short)(u >> 16);
}
__device__ __forceinline__ float bf2f(short s) {
  return __uint_as_float(((unsigned)(unsigned short)s) << 16);
}
__device__ __forceinline__ unsigned packbf(float a, float b) {
  return (unsigned)(unsigned short)bfbits(a) |
         ((unsigned)(unsigned short)bfbits(b) << 16);
}

// ---------------- K1: passA (radix-partition edges, zero cnt) ∥ project ----------------
__global__ __launch_bounds__(512) void k_projA(
    const float* __restrict__ x, const float* __restrict__ Wp,
    const float* __restrict__ bp, unsigned short* __restrict__ h,
    const int* __restrict__ ei, unsigned* __restrict__ seg,
    int* __restrict__ cnt8, int* __restrict__ cnt,
    int n, int nE, int nABlk, unsigned scale, int segCap)
{
  __shared__ uint4 WuP[2048];   // 32KB: [row][unit (j ^ (row&15))], 16B units
  int b = blockIdx.x;
  int tid = threadIdx.x;

  if (b < nABlk) {
    // ---- passA: bin 4096 edges by dst range, write packed (d<<16)|s ----
    int* bcnt = (int*)&WuP[0];
    int* bcur = bcnt + 8;
    if (tid < 8) bcnt[tid] = 0;
    int zi = b * 256 + tid;                 // fold cnt zeroing in
    if (tid < 256 && zi < n) cnt[zi] = 0;
    __syncthreads();
    int base = b * EPB_A;
    int dv[8], sv[8], bv[8];
    bool val[8];
#pragma unroll
    for (int u = 0; u < 8; ++u) {
      int e = base + u * 512 + tid;
      val[u] = (e < nE);
      if (val[u]) {
        dv[u] = ei[nE + e];
        sv[u] = ei[e];
        bv[u] = (int)(((unsigned long long)(unsigned)dv[u] * scale) >> 32);
        atomicAdd(&bcnt[bv[u]], 1);
      }
    }
    __syncthreads();
    if (tid < 8) bcur[tid] = atomicAdd(&cnt8[tid], bcnt[tid]);
    __syncthreads();
#pragma unroll
    for (int u = 0; u < 8; ++u) {
      if (val[u]) {
        int pos = atomicAdd(&bcur[bv[u]], 1);
        if (pos < segCap)
          seg[(size_t)bv[u] * segCap + pos] =
              ((unsigned)dv[u] << 16) | (unsigned)sv[u];
      }
    }
    return;
  }

  // ---- project: stage Wp (f32 -> bf16, swizzled) ----
#pragma unroll
  for (int it = 0; it < 4; ++it) {
    int g = it * 512 + tid;          // unit 0..2047
    int row = g >> 4, j = g & 15;
    const float* src = Wp + row * DD + j * 8;
    float4 f0 = *(const float4*)src;
    float4 f1 = *(const float4*)(src + 4);
    uint4 v;
    v.x = packbf(f0.x, f0.y); v.y = packbf(f0.z, f0.w);
    v.z = packbf(f1.x, f1.y); v.w = packbf(f1.z, f1.w);
    WuP[(row << 4) | (j ^ (row & 15))] = v;
  }
  __syncthreads();

  int l = tid & 63;
  int wv = tid >> 6;
  int row0 = ((b - nABlk) * 8 + wv) * 16;
  if (row0 >= n) return;
  int lr = l & 15, kg = l >> 4;
  int rA = row0 + lr; if (rA > n - 1) rA = n - 1;

  f32x4 acc[8];
#pragma unroll
  for (int cb = 0; cb < 8; ++cb) {
    float bv2 = bp[16 * cb + lr];
    acc[cb] = (f32x4){bv2, bv2, bv2, bv2};
  }

  const float* xrow = x + (size_t)rA * DD;
#pragma unroll
  for (int ks = 0; ks < 4; ++ks) {
    int ko = 32 * ks + 8 * kg;
    float4 f0 = *(const float4*)(xrow + ko);
    float4 f1 = *(const float4*)(xrow + ko + 4);
    float fv[8] = {f0.x, f0.y, f0.z, f0.w, f1.x, f1.y, f1.z, f1.w};
    bf16x8 ah, al;
#pragma unroll
    for (int j = 0; j < 8; ++j) {
      short hb = bfbits(fv[j]);
      ah[j] = hb;
      al[j] = bfbits(fv[j] - bf2f(hb));
    }
    int ju = 4 * ks + kg;
#pragma unroll
    for (int cb = 0; cb < 8; ++cb) {
      int row = 16 * cb + lr;
      bf16x8 bfr = *(const bf16x8*)&WuP[(row << 4) | (ju ^ lr)];
      acc[cb] = __builtin_amdgcn_mfma_f32_16x16x32_bf16(ah, bfr, acc[cb], 0, 0, 0);
      acc[cb] = __builtin_amdgcn_mfma_f32_16x16x32_bf16(al, bfr, acc[cb], 0, 0, 0);
    }
  }

#pragma unroll
  for (int i = 0; i < 4; ++i) {
    int r = row0 + 4 * kg + i;
    if (r < n) {
#pragma unroll
      for (int cb = 0; cb < 8; ++cb) {
        float v = fmaxf(acc[cb][i], 0.f);
        h[(size_t)r * DD + 16 * cb + lr] = (unsigned short)bfbits(v);
      }
    }
  }
}

// ---------------- K2: passB — L2-resident scatter into slot buckets ----------------
__global__ __launch_bounds__(256) void k_passB(
    const unsigned* __restrict__ seg, const int* __restrict__ cnt8,
    int* __restrict__ cnt, unsigned short* __restrict__ slots, int segCap)
{
  int b = blockIdx.x;
  int tid = threadIdx.x;
  int r = b & 7;
  int chunk = b >> 3;
  int len = cnt8[r]; if (len > segCap) len = segCap;
  const unsigned* s = seg + (size_t)r * segCap;
  int base = chunk * EPB_B;
#pragma unroll
  for (int u = 0; u < 8; ++u) {
    int e = base + u * 256 + tid;
    if (e < len) {
      unsigned p = s[e];
      int d = (int)(p >> 16);
      int src = (int)(p & 0xFFFFu);
      int pos = atomicAdd(&cnt[d], 1);
      if (pos < MAXDEG) slots[(size_t)d * MAXDEG + pos] = (unsigned short)src;
    }
  }
}

// ---------------- K3: gather-reduce, 4 nodes per wave (high occupancy) ----------------
__global__ __launch_bounds__(256) void k_gather(
    const int* __restrict__ cnt, const unsigned short* __restrict__ slots,
    const __hip_bfloat162* __restrict__ h2,
    __hip_bfloat162* __restrict__ meanb, int n)
{
  int w = (blockIdx.x * 256 + threadIdx.x) >> 6;
  int l = threadIdx.x & 63;
  int node0 = w * 4;
  if (node0 >= n) return;

#pragma unroll 1
  for (int i = 0; i < 4; ++i) {
    int node = node0 + i;
    if (node >= n) break;
    int dgTrue = cnt[node];
    int dg = dgTrue < MAXDEG ? dgTrue : MAXDEG;
    int myidx = (int)slots[(size_t)node * MAXDEG + l];

    float s0 = 0.f, s1 = 0.f, t0 = 0.f, t1 = 0.f;
    int j = 0;
    for (; j + 8 <= dg; j += 8) {
      int i0 = __builtin_amdgcn_readlane(myidx, j);
      int i1 = __builtin_amdgcn_readlane(myidx, j + 1);
      int i2 = __builtin_amdgcn_readlane(myidx, j + 2);
      int i3 = __builtin_amdgcn_readlane(myidx, j + 3);
      int i4 = __builtin_amdgcn_readlane(myidx, j + 4);
      int i5 = __builtin_amdgcn_readlane(myidx, j + 5);
      int i6 = __builtin_amdgcn_readlane(myidx, j + 6);
      int i7 = __builtin_amdgcn_readlane(myidx, j + 7);
      __hip_bfloat162 v0 = h2[(size_t)i0 * 64 + l];
      __hip_bfloat162 v1 = h2[(size_t)i1 * 64 + l];
      __hip_bfloat162 v2 = h2[(size_t)i2 * 64 + l];
      __hip_bfloat162 v3 = h2[(size_t)i3 * 64 + l];
      __hip_bfloat162 v4 = h2[(size_t)i4 * 64 + l];
      __hip_bfloat162 v5 = h2[(size_t)i5 * 64 + l];
      __hip_bfloat162 v6 = h2[(size_t)i6 * 64 + l];
      __hip_bfloat162 v7 = h2[(size_t)i7 * 64 + l];
      s0 += __bfloat162float(v0.x) + __bfloat162float(v1.x);
      s1 += __bfloat162float(v0.y) + __bfloat162float(v1.y);
      t0 += __bfloat162float(v2.x) + __bfloat162float(v3.x);
      t1 += __bfloat162float(v2.y) + __bfloat162float(v3.y);
      s0 += __bfloat162float(v4.x) + __bfloat162float(v5.x);
      s1 += __bfloat162float(v4.y) + __bfloat162float(v5.y);
      t0 += __bfloat162float(v6.x) + __bfloat162float(v7.x);
      t1 += __bfloat162float(v6.y) + __bfloat162float(v7.y);
    }
    for (; j < dg; ++j) {
      int i0 = __builtin_amdgcn_readlane(myidx, j);
      __hip_bfloat162 v0 = h2[(size_t)i0 * 64 + l];
      s0 += __bfloat162float(v0.x);
      s1 += __bfloat162float(v0.y);
    }
    s0 += t0; s1 += t1;
    float rd = 1.0f / fmaxf((float)dgTrue, 1.0f);
    __hip_bfloat162 o;
    o.x = __float2bfloat16(s0 * rd);
    o.y = __float2bfloat16(s1 * rd);
    meanb[(size_t)node * 64 + l] = o;
  }
}

// ---------------- K4: combine v2 — 512 thr, W (f32->bf16) in swizzled LDS, col-split ----------------
__global__ __launch_bounds__(512) void k_combine(
    const float* __restrict__ x, const float* __restrict__ Wl,
    const float* __restrict__ bl, const float* __restrict__ Wr,
    const unsigned short* __restrict__ meanb,
    float* __restrict__ out, int n)
{
  __shared__ uint4 Wu[4096];       // 64KB: [mat][row][unit (j ^ (row&15))]
  __shared__ float ssh[4 * 32];    // [rg][half][16 rows]

  int tid = threadIdx.x;

  // stage Wl (mat 0) + Wr (mat 1) from f32, 16B units, XOR-swizzled within each row
#pragma unroll
  for (int it = 0; it < 8; ++it) {
    int g = it * 512 + tid;       // 0..4095
    int mat = g >> 11, rem = g & 2047;
    int row = rem >> 4, j = rem & 15;
    const float* src = (mat ? Wr : Wl) + row * DD + j * 8;
    float4 f0 = *(const float4*)src;
    float4 f1 = *(const float4*)(src + 4);
    uint4 v;
    v.x = packbf(f0.x, f0.y); v.y = packbf(f0.z, f0.w);
    v.z = packbf(f1.x, f1.y); v.w = packbf(f1.z, f1.w);
    Wu[(mat << 11) | (row << 4) | (j ^ (row & 15))] = v;
  }
  __syncthreads();

  int l = tid & 63;
  int wv = tid >> 6;        // 0..7
  int rg = wv >> 1;         // 0..3
  int half = wv & 1;        // 0..1
  int row0 = (blockIdx.x * 4 + rg) * 16;
  int lr = l & 15, kg = l >> 4;
  bool active = (row0 < n);

  f32x4 acc[4];
  float ss[4] = {0.f, 0.f, 0.f, 0.f};

  if (active) {
    int rA = row0 + lr; if (rA > n - 1) rA = n - 1;
#pragma unroll
    for (int q = 0; q < 4; ++q) {
      float bv = bl[16 * (4 * half + q) + lr];
      acc[q] = (f32x4){bv, bv, bv, bv};
    }

    const unsigned short* mrow = meanb + (size_t)rA * DD;
    const float* xrow = x + (size_t)rA * DD;
#pragma unroll
    for (int ks = 0; ks < 4; ++ks) {
      int ko = 32 * ks + 8 * kg;
      bf16x8 a = *(const bf16x8*)(mrow + ko);
      float4 f0 = *(const float4*)(xrow + ko);
      float4 f1 = *(const float4*)(xrow + ko + 4);
      float fv[8] = {f0.x, f0.y, f0.z, f0.w, f1.x, f1.y, f1.z, f1.w};
      bf16x8 ah, al;
#pragma unroll
      for (int jj = 0; jj < 8; ++jj) {
        short hb = bfbits(fv[jj]);
        ah[jj] = hb;
        al[jj] = bfbits(fv[jj] - bf2f(hb));
      }
      int ju = 4 * ks + kg;
#pragma unroll
      for (int q = 0; q < 4; ++q) {
        int row = 16 * (4 * half + q) + lr;
        bf16x8 bL = *(const bf16x8*)&Wu[(0 << 11) | (row << 4) | (ju ^ lr)];
        bf16x8 bR = *(const bf16x8*)&Wu[(1 << 11) | (row << 4) | (ju ^ lr)];
        acc[q] = __builtin_amdgcn_mfma_f32_16x16x32_bf16(a,  bL, acc[q], 0, 0, 0);
        acc[q] = __builtin_amdgcn_mfma_f32_16x16x32_bf16(ah, bR, acc[q], 0, 0, 0);
        acc[q] = __builtin_amdgcn_mfma_f32_16x16x32_bf16(al, bR, acc[q], 0, 0, 0);
      }
    }

    // ELU + partial row-norm (this wave's 64 cols)
#pragma unroll
    for (int q = 0; q < 4; ++q) {
#pragma unroll
      for (int i = 0; i < 4; ++i) {
        float z = acc[q][i];
        z = z > 0.f ? z : expm1f(z);
        acc[q][i] = z;
        ss[i] += z * z;
      }
    }
#pragma unroll
    for (int i = 0; i < 4; ++i) {
#pragma unroll
      for (int m2 = 1; m2 < 16; m2 <<= 1) ss[i] += __shfl_xor(ss[i], m2);
    }
    if (lr == 0) {
#pragma unroll
      for (int i = 0; i < 4; ++i) ssh[rg * 32 + half * 16 + 4 * kg + i] = ss[i];
    }
  }
  __syncthreads();

  if (active) {
#pragma unroll
    for (int i = 0; i < 4; ++i) {
      int r = row0 + 4 * kg + i;
      if (r < n) {
        float tot = ssh[rg * 32 + 4 * kg + i] + ssh[rg * 32 + 16 + 4 * kg + i];
        float inv = 1.f / fmaxf(sqrtf(tot), EPSN);
#pragma unroll
        for (int q = 0; q < 4; ++q) {
          int c = 16 * (4 * half + q) + lr;
          out[(size_t)r * DD + c] = x[(size_t)r * DD + c] + acc[q][i] * inv;
        }
      }
    }
  }
}

extern "C" void kernel_launch(void* const* d_in, const int* in_sizes, int n_in,
                              void* d_out, int out_size, void* d_ws, size_t ws_size,
                              hipStream_t stream) {
  const float* x  = (const float*)d_in[0];
  const int*   ei = (const int*)d_in[1];
  const float* Wp = (const float*)d_in[2];
  const float* bp = (const float*)d_in[3];
  const float* Wl = (const float*)d_in[4];
  const float* bl = (const float*)d_in[5];
  const float* Wr = (const float*)d_in[6];
  float* out = (float*)d_out;

  int n  = in_sizes[0] / DD;   // 50000
  int nE = in_sizes[1] / 2;    // 800000
  int segCap = nE / 8 + 16384; // 116384 (55-sigma margin)
  unsigned scale = (unsigned)((((unsigned long long)8) << 32) / (unsigned long long)n);

  // ws layout (256B-aligned): h | meanb | cnt | cnt8 | slots | seg
  auto align256 = [](size_t v) { return (v + 255) & ~(size_t)255; };
  char* p = (char*)d_ws;
  unsigned short* h = (unsigned short*)p;      p += align256((size_t)n * DD * 2);
  unsigned short* meanb = (unsigned short*)p;  p += align256((size_t)n * DD * 2);
  int* cnt  = (int*)p;                         p += align256((size_t)n * 4);
  int* cnt8 = (int*)p;                         p += 256;
  unsigned short* slots = (unsigned short*)p;  p += align256((size_t)n * MAXDEG * 2);
  unsigned* seg = (unsigned*)p;                p += align256((size_t)8 * segCap * 4);

  hipMemsetAsync(cnt8, 0, 256, stream);

  int nABlk = (nE + EPB_A - 1) / EPB_A;         // 196
  int nPBlk = (n + 127) / 128;                  // 391
  k_projA<<<nABlk + nPBlk, 512, 0, stream>>>(
      x, Wp, bp, h, ei, seg, cnt8, cnt, n, nE, nABlk, scale, segCap);

  int nChunkB = (segCap + EPB_B - 1) / EPB_B;   // 57
  k_passB<<<8 * nChunkB, 256, 0, stream>>>(seg, cnt8, cnt, slots, segCap);

  int nGWaves = (n + 3) / 4;                    // 12500
  int nGBlk   = (nGWaves + 3) / 4;              // 3125
  k_gather<<<nGBlk, 256, 0, stream>>>(
      cnt, slots, (const __hip_bfloat162*)h, (__hip_bfloat162*)meanb, n);

  int nCBlk = (n + 63) / 64;                    // 782
  k_combine<<<nCBlk, 512, 0, stream>>>(x, Wl, bl, Wr, meanb, out, n);
}